// Round 5
// baseline (595.324 us; speedup 1.0000x reference)
//
#include <hip/hip_runtime.h>

typedef unsigned short u16;
typedef __attribute__((ext_vector_type(8))) __bf16 bf16x8;
typedef __attribute__((ext_vector_type(8))) unsigned short u16x8;
typedef __attribute__((ext_vector_type(4))) unsigned short u16x4;
typedef __attribute__((ext_vector_type(4))) float f32x4;

#define BM 128
#define BN 128
#define BK 32

__device__ __forceinline__ float bf2f(u16 x) {
  union { unsigned int u; float f; } un;
  un.u = ((unsigned int)x) << 16;
  return un.f;
}

__device__ __forceinline__ u16 f2bf(float f) {
  union { float f; unsigned int u; } un;
  un.f = f;
  unsigned int r = un.u + 0x7fffu + ((un.u >> 16) & 1u);
  return (u16)(r >> 16);
}

__device__ __forceinline__ void cstore(u16* p, float v)   { *p = f2bf(v); }
__device__ __forceinline__ void cstore(float* p, float v) { *p = v; }

// async global->LDS, 16B per lane; lds dst is wave-uniform base (HW adds lane*16B)
__device__ __forceinline__ void async_ld16(const u16* g, u16* l) {
  __builtin_amdgcn_global_load_lds(
      (const __attribute__((address_space(1))) unsigned int*)g,
      (__attribute__((address_space(3))) unsigned int*)l, 16, 0, 0);
}

// ---------------- fp32 -> bf16 elementwise (x), 4 elems/thread ----------------
__global__ __launch_bounds__(256)
void f32_to_bf16(const float* __restrict__ s, u16* __restrict__ d)
{
  const int i = blockIdx.x * 256 + threadIdx.x;
  const float4 v = ((const float4*)s)[i];
  u16x4 o;
  o.x = f2bf(v.x); o.y = f2bf(v.y); o.z = f2bf(v.z); o.w = f2bf(v.w);
  ((u16x4*)d)[i] = o;
}

// ---------------- fp32 [R][CC] -> bf16 transposed [CC][R] ----------------
__global__ __launch_bounds__(256)
void transpose_f2b(const float* __restrict__ src, int sld,
                   u16* __restrict__ dst, int dld)
{
  __shared__ float tile[32][33];
  const int c0 = blockIdx.x * 32;
  const int r0 = blockIdx.y * 32;
  const int tx = threadIdx.x;   // 0..31
  const int ty = threadIdx.y;   // 0..7
#pragma unroll
  for (int i = ty; i < 32; i += 8)
    tile[i][tx] = src[(long long)(r0 + i) * sld + c0 + tx];
  __syncthreads();
#pragma unroll
  for (int i = ty; i < 32; i += 8)
    dst[(long long)(c0 + i) * dld + r0 + tx] = f2bf(tile[tx][i]);
}

// ---------------- bf16 [R][CC] (strided, batched) -> bf16 [CC][R] ----------------
__global__ __launch_bounds__(256)
void transpose_bf16(const u16* __restrict__ src, int sld, long long sbs,
                    u16* __restrict__ dst, int dld, long long dbs)
{
  src += (long long)blockIdx.z * sbs;
  dst += (long long)blockIdx.z * dbs;
  __shared__ u16 tile[32][33];
  const int c0 = blockIdx.x * 32;
  const int r0 = blockIdx.y * 32;
  const int tx = threadIdx.x;
  const int ty = threadIdx.y;
#pragma unroll
  for (int i = ty; i < 32; i += 8)
    tile[i][tx] = src[(long long)(r0 + i) * sld + c0 + tx];
  __syncthreads();
#pragma unroll
  for (int i = ty; i < 32; i += 8)
    dst[(long long)(c0 + i) * dld + r0 + tx] = tile[tx][i];
}

// C[M][N] = A[M][K] * Bt[N][K]^T  (NT GEMM), bf16 in, fp32 accum, OT out.
// mode 0: plain; mode 1: causal skip (tile fully above diagonal -> return);
// mode 2: trim K to (bx+1)*BM (for P@V with causal-zeroed probs).
template <typename OT>
__global__ __launch_bounds__(256)
void gemm_nt(const u16* __restrict__ A, int lda, long long sA,
             const u16* __restrict__ Bt, int ldb, long long sB,
             OT* __restrict__ Cp, int ldc, long long sC,
             int K, const float* __restrict__ bias, float scale, int mode)
{
  const int bx = blockIdx.x, by = blockIdx.y, bz = blockIdx.z;
  if (mode == 1 && by > bx) return;
  A  += (long long)bz * sA;
  Bt += (long long)bz * sB;
  Cp += (long long)bz * sC;
  int kEnd = K;
  if (mode == 2) { int ke = (bx + 1) * BM; kEnd = ke < K ? ke : K; }

  __shared__ __align__(16) u16 As[BM * BK];   // 8 KB, row-major [128][32]
  __shared__ __align__(16) u16 Bs[BN * BK];   // 8 KB

  const int tid  = threadIdx.x;
  const int wave = tid >> 6;
  const int lane = tid & 63;
  const int l16  = lane & 15;
  const int quad = lane >> 4;
  const int wm = (wave >> 1) * 64;
  const int wn = (wave & 1) * 64;

  // one chunk = 1 KB = 16 rows x 32 cols; lane l lands at LDS byte chunk*1024 + 16*l,
  // which equals row-major (row = chunk*16 + l/4, col = (l%4)*8). 8 chunks/tile;
  // wave w stages chunks {2w, 2w+1} of As AND Bs.
  const int srow = lane >> 2;
  const int scol = (lane & 3) * 8;

  const u16* Ag = A  + (long long)(bx * BM) * lda + scol;
  const u16* Bg = Bt + (long long)(by * BN) * ldb + scol;

  f32x4 zero4;
  zero4.x = zero4.y = zero4.z = zero4.w = 0.0f;
  f32x4 acc[4][4];
#pragma unroll
  for (int i = 0; i < 4; ++i)
#pragma unroll
    for (int j = 0; j < 4; ++j) acc[i][j] = zero4;

  for (int k0 = 0; k0 < kEnd; k0 += BK) {
#pragma unroll
    for (int it = 0; it < 2; ++it) {
      const int chunk = wave * 2 + it;         // 0..7
      const int r = chunk * 16 + srow;         // 0..127
      async_ld16(Ag + (long long)r * lda + k0, &As[chunk * 512]);
      async_ld16(Bg + (long long)r * ldb + k0, &Bs[chunk * 512]);
    }
    __syncthreads();

    bf16x8 av[4], bv[4];
#pragma unroll
    for (int i = 0; i < 4; ++i) {
      union { u16x8 u; bf16x8 b; } ca, cb;
      ca.u = *(const u16x8*)(As + (wm + i * 16 + l16) * BK + quad * 8);
      cb.u = *(const u16x8*)(Bs + (wn + i * 16 + l16) * BK + quad * 8);
      av[i] = ca.b;
      bv[i] = cb.b;
    }
#pragma unroll
    for (int i = 0; i < 4; ++i)
#pragma unroll
      for (int j = 0; j < 4; ++j)
        acc[i][j] = __builtin_amdgcn_mfma_f32_16x16x32_bf16(av[i], bv[j], acc[i][j], 0, 0, 0);
    __syncthreads();
  }

  // epilogue: C/D layout col = lane&15, row = quad*4 + reg (verified m89/m91)
  const int row0 = bx * BM + wm + quad * 4;
  const int col0 = by * BN + wn + l16;
#pragma unroll
  for (int j = 0; j < 4; ++j) {
    const int col = col0 + j * 16;
    const float bval = bias ? bias[col] : 0.0f;
#pragma unroll
    for (int i = 0; i < 4; ++i) {
#pragma unroll
      for (int r = 0; r < 4; ++r) {
        const int row = row0 + i * 16 + r;
        cstore(&Cp[(long long)row * ldc + col], acc[i][j][r] * scale + bval);
      }
    }
  }
}

// causal softmax over one row of [T] bf16 scores, in place; zeros the masked tail.
// requires T == 2048 (8 elems/thread * 256 threads)
__global__ __launch_bounds__(256)
void softmax_causal(u16* __restrict__ sc, int T)
{
  const int row = blockIdx.x;       // z*T + t
  const int t = row & (T - 1);
  u16* p = sc + (long long)row * T;
  const int L = t + 1;
  const int tid = threadIdx.x;
  const int lane = tid & 63;
  const int wave = tid >> 6;

  float v[8];
  float m = -1e30f;
#pragma unroll
  for (int j = 0; j < 8; ++j) {
    int i = tid + j * 256;
    if (i < L) { v[j] = bf2f(p[i]); m = fmaxf(m, v[j]); }
    else v[j] = -1e30f;
  }
#pragma unroll
  for (int o = 32; o > 0; o >>= 1) m = fmaxf(m, __shfl_xor(m, o, 64));
  __shared__ float redm[4], reds[4];
  if (lane == 0) redm[wave] = m;
  __syncthreads();
  m = fmaxf(fmaxf(redm[0], redm[1]), fmaxf(redm[2], redm[3]));

  float s = 0.0f;
#pragma unroll
  for (int j = 0; j < 8; ++j) {
    int i = tid + j * 256;
    if (i < L) { float e = __expf(v[j] - m); v[j] = e; s += e; }
    else v[j] = 0.0f;
  }
#pragma unroll
  for (int o = 32; o > 0; o >>= 1) s += __shfl_xor(s, o, 64);
  if (lane == 0) reds[wave] = s;
  __syncthreads();
  s = reds[0] + reds[1] + reds[2] + reds[3];
  const float inv = 1.0f / s;
#pragma unroll
  for (int j = 0; j < 8; ++j) {
    int i = tid + j * 256;
    p[i] = f2bf(v[j] * inv);   // masked lanes have v[j]=0 -> writes 0
  }
}

extern "C" void kernel_launch(void* const* d_in, const int* in_sizes, int n_in,
                              void* d_out, int out_size, void* d_ws, size_t ws_size,
                              hipStream_t stream)
{
  (void)in_sizes; (void)n_in; (void)out_size; (void)ws_size;
  const int B = 8, T = 2048, C = 1024;
  const int M = B * T;        // 16384
  const int C3 = 3 * C;       // 3072

  // inputs AND output are FP32 (reference dtypes; harness rule: fp32 ref -> float* d_out)
  const float* x     = (const float*)d_in[0];
  const float* Wkqv  = (const float*)d_in[1];
  const float* bkqv  = (const float*)d_in[2];
  const float* Wproj = (const float*)d_in[3];
  const float* bproj = (const float*)d_in[4];
  float* out = (float*)d_out;

  // Workspace: 232 MiB footprint (proven to fit). xb dead after GEMM1; ao aliases it.
  char* w = (char*)d_ws;
  u16* xb     = (u16*)w; w += (size_t)M * C * 2;        // 33.5 MB [M][C]  (aliased by ao)
  u16* WkqvT  = (u16*)w; w += (size_t)C3 * C * 2;       //  6.3 MB [3C][C]
  u16* WprojT = (u16*)w; w += (size_t)C * C * 2;        //  2.1 MB [C][C]
  u16* kqv    = (u16*)w; w += (size_t)M * C3 * 2;       // 100.7 MB [M][3C]
  u16* vT     = (u16*)w; w += (size_t)B * C * T * 2;    // 33.5 MB [B][C][T]
  u16* sc     = (u16*)w; w += (size_t)B * T * T * 2;    // 67.1 MB [B][T][T]
  u16* ao     = xb;                                     // alias: lifetimes disjoint

  dim3 tb(32, 8);

  // x -> bf16
  f32_to_bf16<<<(M * C) / 1024, 256, 0, stream>>>(x, xb);

  // weights -> bf16, NT layout
  transpose_f2b<<<dim3(C3 / 32, C / 32, 1), tb, 0, stream>>>(Wkqv, C3, WkqvT, C);
  transpose_f2b<<<dim3(C / 32, C / 32, 1), tb, 0, stream>>>(Wproj, C, WprojT, C);

  // kqv = x @ W_kqv + b_kqv    [M][3C]   (split order: k | q | v)
  gemm_nt<u16><<<dim3(M / BM, C3 / BN, 1), 256, 0, stream>>>(
      xb, C, 0, WkqvT, C, 0, kqv, C3, 0, C, bkqv, 1.0f, 0);

  // v[T][C] (stride 3C, per batch) -> vT[C][T]
  transpose_bf16<<<dim3(C / 32, T / 32, B), tb, 0, stream>>>(
      kqv + 2 * C, C3, (long long)T * C3, vT, T, (long long)C * T);

  // scores = q @ k^T * (1/sqrt(T)), lower-triangular tiles only
  gemm_nt<u16><<<dim3(T / BM, T / BN, B), 256, 0, stream>>>(
      kqv + C, C3, (long long)T * C3, kqv, C3, (long long)T * C3,
      sc, T, (long long)T * T, C, nullptr, 0.022097086912079608f, 1);

  // causal softmax in place (writes zeros above diagonal)
  softmax_causal<<<B * T, 256, 0, stream>>>(sc, T);

  // ao = probs @ v  (NT against vT), K trimmed per tile row; ao aliases xb (xb dead)
  gemm_nt<u16><<<dim3(T / BM, C / BN, B), 256, 0, stream>>>(
      sc, T, (long long)T * T, vT, T, (long long)C * T,
      ao, C, (long long)T * C, T, nullptr, 1.0f, 2);

  // out = ao @ W_proj + b_proj   -- FP32 output
  gemm_nt<float><<<dim3(M / BM, C / BN, 1), 256, 0, stream>>>(
      ao, C, 0, WprojT, C, 0, out, C, 0, C, bproj, 1.0f, 0);
}

// Round 6
// 545.018 us; speedup vs baseline: 1.0923x; 1.0923x over previous
//
#include <hip/hip_runtime.h>

typedef unsigned short u16;
typedef __attribute__((ext_vector_type(8))) __bf16 bf16x8;
typedef __attribute__((ext_vector_type(8))) unsigned short u16x8;
typedef __attribute__((ext_vector_type(4))) unsigned short u16x4;
typedef __attribute__((ext_vector_type(4))) float f32x4;

#define BM 128
#define BN 128
#define BK 32   // per LDS buffer; K-loop steps 2*BK with twin buffers

__device__ __forceinline__ float bf2f(u16 x) {
  union { unsigned int u; float f; } un;
  un.u = ((unsigned int)x) << 16;
  return un.f;
}

__device__ __forceinline__ u16 f2bf(float f) {
  union { float f; unsigned int u; } un;
  un.f = f;
  unsigned int r = un.u + 0x7fffu + ((un.u >> 16) & 1u);
  return (u16)(r >> 16);
}

__device__ __forceinline__ void cstore(u16* p, float v)   { *p = f2bf(v); }
__device__ __forceinline__ void cstore(float* p, float v) { *p = v; }

// async global->LDS, 16B per lane; lds dst is wave-uniform base (HW adds lane*16B)
__device__ __forceinline__ void async_ld16(const u16* g, u16* l) {
  __builtin_amdgcn_global_load_lds(
      (const __attribute__((address_space(1))) unsigned int*)g,
      (__attribute__((address_space(3))) unsigned int*)l, 16, 0, 0);
}

// ---------------- fp32 -> bf16 elementwise (x), 4 elems/thread ----------------
__global__ __launch_bounds__(256)
void f32_to_bf16(const float* __restrict__ s, u16* __restrict__ d)
{
  const int i = blockIdx.x * 256 + threadIdx.x;
  const float4 v = ((const float4*)s)[i];
  u16x4 o;
  o.x = f2bf(v.x); o.y = f2bf(v.y); o.z = f2bf(v.z); o.w = f2bf(v.w);
  ((u16x4*)d)[i] = o;
}

// ---------------- fp32 [R][CC] -> bf16 transposed [CC][R] ----------------
__global__ __launch_bounds__(256)
void transpose_f2b(const float* __restrict__ src, int sld,
                   u16* __restrict__ dst, int dld)
{
  __shared__ float tile[32][33];
  const int c0 = blockIdx.x * 32;
  const int r0 = blockIdx.y * 32;
  const int tx = threadIdx.x;   // 0..31
  const int ty = threadIdx.y;   // 0..7
#pragma unroll
  for (int i = ty; i < 32; i += 8)
    tile[i][tx] = src[(long long)(r0 + i) * sld + c0 + tx];
  __syncthreads();
#pragma unroll
  for (int i = ty; i < 32; i += 8)
    dst[(long long)(c0 + i) * dld + r0 + tx] = f2bf(tile[tx][i]);
}

// ---------------- bf16 [R][CC] (strided, batched) -> bf16 [CC][R] ----------------
__global__ __launch_bounds__(256)
void transpose_bf16(const u16* __restrict__ src, int sld, long long sbs,
                    u16* __restrict__ dst, int dld, long long dbs)
{
  src += (long long)blockIdx.z * sbs;
  dst += (long long)blockIdx.z * dbs;
  __shared__ u16 tile[32][33];
  const int c0 = blockIdx.x * 32;
  const int r0 = blockIdx.y * 32;
  const int tx = threadIdx.x;
  const int ty = threadIdx.y;
#pragma unroll
  for (int i = ty; i < 32; i += 8)
    tile[i][tx] = src[(long long)(r0 + i) * sld + c0 + tx];
  __syncthreads();
#pragma unroll
  for (int i = ty; i < 32; i += 8)
    dst[(long long)(c0 + i) * dld + r0 + tx] = tile[tx][i];
}

// C[M][N] = A[M][K] * Bt[N][K]^T  (NT GEMM), bf16 in, fp32 accum, OT out.
// mode 0: plain; mode 1: causal skip (tile fully above diagonal -> return);
// mode 2: trim K to (bx+1)*BM (P@V with causal-zeroed probs);
// mode 3: plain, swapped block decode (bx=blockIdx.y) for A-tile L2 reuse.
// K (or trimmed kEnd) must be a multiple of 64.
template <typename OT>
__global__ __launch_bounds__(256)
void gemm_nt(const u16* __restrict__ A, int lda, long long sA,
             const u16* __restrict__ Bt, int ldb, long long sB,
             OT* __restrict__ Cp, int ldc, long long sC,
             int K, const float* __restrict__ bias, float scale, int mode)
{
  int bx = blockIdx.x, by = blockIdx.y;
  const int bz = blockIdx.z;
  if (mode == 3) { bx = blockIdx.y; by = blockIdx.x; }
  if (mode == 1 && by > bx) return;
  A  += (long long)bz * sA;
  Bt += (long long)bz * sB;
  Cp += (long long)bz * sC;
  int kEnd = K;
  if (mode == 2) { int ke = (bx + 1) * BM; kEnd = ke < K ? ke : K; }

  // twin BK=32 buffers -> 64-wide K step, half the barriers, 32 KB LDS total
  __shared__ __align__(16) u16 As[2][BM * BK];
  __shared__ __align__(16) u16 Bs[2][BN * BK];

  const int tid  = threadIdx.x;
  const int wave = tid >> 6;
  const int lane = tid & 63;
  const int l16  = lane & 15;
  const int quad = lane >> 4;
  const int wm = (wave >> 1) * 64;
  const int wn = (wave & 1) * 64;

  // one chunk = 1 KB = 16 rows x 32 cols; lane l lands at byte chunk*1024 + 16*l
  // = row-major (row = chunk*16 + l/4, col = (l%4)*8). 8 chunks per buffer;
  // wave w stages chunks {2w, 2w+1} of each of As[0],As[1],Bs[0],Bs[1].
  const int srow = lane >> 2;
  const int scol = (lane & 3) * 8;

  const u16* Ag = A  + (long long)(bx * BM) * lda + scol;
  const u16* Bg = Bt + (long long)(by * BN) * ldb + scol;

  f32x4 zero4;
  zero4.x = zero4.y = zero4.z = zero4.w = 0.0f;
  f32x4 acc[4][4];
#pragma unroll
  for (int i = 0; i < 4; ++i)
#pragma unroll
    for (int j = 0; j < 4; ++j) acc[i][j] = zero4;

  for (int k0 = 0; k0 < kEnd; k0 += 2 * BK) {
#pragma unroll
    for (int h = 0; h < 2; ++h) {
#pragma unroll
      for (int it = 0; it < 2; ++it) {
        const int chunk = wave * 2 + it;         // 0..7
        const int r = chunk * 16 + srow;         // 0..127
        async_ld16(Ag + (long long)r * lda + k0 + h * BK, &As[h][chunk * 512]);
        async_ld16(Bg + (long long)r * ldb + k0 + h * BK, &Bs[h][chunk * 512]);
      }
    }
    __syncthreads();

#pragma unroll
    for (int h = 0; h < 2; ++h) {
      bf16x8 av[4], bv[4];
#pragma unroll
      for (int i = 0; i < 4; ++i) {
        union { u16x8 u; bf16x8 b; } ca, cb;
        ca.u = *(const u16x8*)(&As[h][0] + (wm + i * 16 + l16) * BK + quad * 8);
        cb.u = *(const u16x8*)(&Bs[h][0] + (wn + i * 16 + l16) * BK + quad * 8);
        av[i] = ca.b;
        bv[i] = cb.b;
      }
#pragma unroll
      for (int i = 0; i < 4; ++i)
#pragma unroll
        for (int j = 0; j < 4; ++j)
          acc[i][j] = __builtin_amdgcn_mfma_f32_16x16x32_bf16(av[i], bv[j], acc[i][j], 0, 0, 0);
    }
    __syncthreads();
  }

  // epilogue: C/D layout col = lane&15, row = quad*4 + reg (verified m89/m91)
  const int row0 = bx * BM + wm + quad * 4;
  const int col0 = by * BN + wn + l16;
#pragma unroll
  for (int j = 0; j < 4; ++j) {
    const int col = col0 + j * 16;
    const float bval = bias ? bias[col] : 0.0f;
#pragma unroll
    for (int i = 0; i < 4; ++i) {
#pragma unroll
      for (int r = 0; r < 4; ++r) {
        const int row = row0 + i * 16 + r;
        cstore(&Cp[(long long)row * ldc + col], acc[i][j][r] * scale + bval);
      }
    }
  }
}

// causal softmax over one row of [T] bf16 scores, in place.
// Vectorized: thread t owns elements [8t, 8t+8). Writes only [0, Lw) where
// Lw = ceil(L/128)*128 — exactly the range the K-trimmed PV GEMM reads.
// requires T == 2048 (8 elems/thread * 256 threads)
__global__ __launch_bounds__(256)
void softmax_causal(u16* __restrict__ sc, int T)
{
  const int row = blockIdx.x;       // z*T + t
  const int t = row & (T - 1);
  u16* p = sc + (long long)row * T;
  const int L  = t + 1;
  const int Lw = ((t >> 7) + 1) << 7;
  const int tid = threadIdx.x;
  const int lane = tid & 63;
  const int wave = tid >> 6;
  const int base = tid * 8;

  const u16x8 in = *(const u16x8*)(p + base);
  float v[8];
  float m = -1e30f;
#pragma unroll
  for (int e = 0; e < 8; ++e) {
    const float f = bf2f(in[e]);
    v[e] = (base + e < L) ? f : -1e30f;
    m = fmaxf(m, v[e]);
  }
#pragma unroll
  for (int o = 32; o > 0; o >>= 1) m = fmaxf(m, __shfl_xor(m, o, 64));
  __shared__ float redm[4], reds[4];
  if (lane == 0) redm[wave] = m;
  __syncthreads();
  m = fmaxf(fmaxf(redm[0], redm[1]), fmaxf(redm[2], redm[3]));

  float s = 0.0f;
#pragma unroll
  for (int e = 0; e < 8; ++e) {
    const float ex = __expf(v[e] - m);       // v==-1e30 -> 0
    v[e] = (base + e < L) ? ex : 0.0f;
    s += v[e];
  }
#pragma unroll
  for (int o = 32; o > 0; o >>= 1) s += __shfl_xor(s, o, 64);
  if (lane == 0) reds[wave] = s;
  __syncthreads();
  s = reds[0] + reds[1] + reds[2] + reds[3];
  const float inv = 1.0f / s;

  if (base < Lw) {
    u16x8 o8;
#pragma unroll
    for (int e = 0; e < 8; ++e) o8[e] = f2bf(v[e] * inv);
    *(u16x8*)(p + base) = o8;
  }
}

extern "C" void kernel_launch(void* const* d_in, const int* in_sizes, int n_in,
                              void* d_out, int out_size, void* d_ws, size_t ws_size,
                              hipStream_t stream)
{
  (void)in_sizes; (void)n_in; (void)out_size; (void)ws_size;
  const int B = 8, T = 2048, C = 1024;
  const int M = B * T;        // 16384
  const int C3 = 3 * C;       // 3072

  // inputs AND output are FP32 (reference dtypes)
  const float* x     = (const float*)d_in[0];
  const float* Wkqv  = (const float*)d_in[1];
  const float* bkqv  = (const float*)d_in[2];
  const float* Wproj = (const float*)d_in[3];
  const float* bproj = (const float*)d_in[4];
  float* out = (float*)d_out;

  // Workspace: 232 MiB footprint (proven to fit). xb dead after GEMM1; ao aliases it.
  char* w = (char*)d_ws;
  u16* xb     = (u16*)w; w += (size_t)M * C * 2;        // 33.5 MB [M][C]  (aliased by ao)
  u16* WkqvT  = (u16*)w; w += (size_t)C3 * C * 2;       //  6.3 MB [3C][C]
  u16* WprojT = (u16*)w; w += (size_t)C * C * 2;        //  2.1 MB [C][C]
  u16* kqv    = (u16*)w; w += (size_t)M * C3 * 2;       // 100.7 MB [M][3C]
  u16* vT     = (u16*)w; w += (size_t)B * C * T * 2;    // 33.5 MB [B][C][T]
  u16* sc     = (u16*)w; w += (size_t)B * T * T * 2;    // 67.1 MB [B][T][T]
  u16* ao     = xb;                                     // alias: lifetimes disjoint

  dim3 tb(32, 8);

  // x -> bf16
  f32_to_bf16<<<(M * C) / 1024, 256, 0, stream>>>(x, xb);

  // weights -> bf16, NT layout
  transpose_f2b<<<dim3(C3 / 32, C / 32, 1), tb, 0, stream>>>(Wkqv, C3, WkqvT, C);
  transpose_f2b<<<dim3(C / 32, C / 32, 1), tb, 0, stream>>>(Wproj, C, WprojT, C);

  // kqv = x @ W_kqv + b_kqv  [M][3C]. mode 3: N fastest -> consecutive blocks
  // share the x row-tile (less HBM refetch).
  gemm_nt<u16><<<dim3(C3 / BN, M / BM, 1), 256, 0, stream>>>(
      xb, C, 0, WkqvT, C, 0, kqv, C3, 0, C, bkqv, 1.0f, 3);

  // v[T][C] (stride 3C, per batch) -> vT[C][T]
  transpose_bf16<<<dim3(C / 32, T / 32, B), tb, 0, stream>>>(
      kqv + 2 * C, C3, (long long)T * C3, vT, T, (long long)C * T);

  // scores = q @ k^T * (1/sqrt(T)), lower-triangular tiles only
  gemm_nt<u16><<<dim3(T / BM, T / BN, B), 256, 0, stream>>>(
      kqv + C, C3, (long long)T * C3, kqv, C3, (long long)T * C3,
      sc, T, (long long)T * T, C, nullptr, 0.022097086912079608f, 1);

  // causal softmax in place (writes zeros through the diagonal tile only)
  softmax_causal<<<B * T, 256, 0, stream>>>(sc, T);

  // ao = probs @ v  (NT against vT), K trimmed per tile row; ao aliases xb
  gemm_nt<u16><<<dim3(T / BM, C / BN, B), 256, 0, stream>>>(
      sc, T, (long long)T * T, vT, T, (long long)C * T,
      ao, C, (long long)T * C, T, nullptr, 1.0f, 2);

  // out = ao @ W_proj + b_proj   -- FP32 output
  gemm_nt<float><<<dim3(M / BM, C / BN, 1), 256, 0, stream>>>(
      ao, C, 0, WprojT, C, 0, out, C, 0, C, bproj, 1.0f, 0);
}